// Round 6
// baseline (3464.553 us; speedup 1.0000x reference)
//
#include <hip/hip_runtime.h>
#include <math.h>

#define TT 1024
#define BB 64
#define II 128
#define HH 256
#define OO 128
#define KR 384           // II + HH rows of [W;U]
#define GPB 16           // blocks per group
#define NCOL 64          // gate-columns per block
#define WS_STRIDE 68     // padded LDS row stride (floats), 16B-aligned
#define Z_STRIDE 392     // padded z row stride per batch (floats)
#define PART_BG_STRIDE 68
#define PART_RC_STRIDE 273

// LDS layout (float offsets)
#define OFF_WS   0                          // 384*68 = 26112
#define OFF_Z    26112                      // 4*392  = 1568
#define OFF_PART (OFF_Z + 4*Z_STRIDE)       // 16*273 = 4368
#define OFF_GB   (OFF_PART + 16*PART_RC_STRIDE)
#define OFF_CST  (OFF_GB + 256)
#define OFF_BIA  (OFF_CST + 64)
#define OFF_MISC (OFF_BIA + 64)
#define LDS_FLOATS (OFF_MISC + 8)
#define LDS_BYTES  (LDS_FLOATS * 4)

// ws layout: abort @int 0; tagged hbuf [2][64][256] u64 @byte 16384 (256KB)
#define WS_HBUF_B 16384
#define WS_CLEAR_B (WS_HBUF_B + 2 * BB * HH * 8)

typedef unsigned long long u64;

__device__ __forceinline__ float rcp(float v) { return __builtin_amdgcn_rcpf(v); }
__device__ __forceinline__ float sigm(float v) { return rcp(1.f + __expf(-v)); }
__device__ __forceinline__ float ftanh(float v) {
    return __builtin_fmaf(-2.f, rcp(__expf(2.f * v) + 1.f), 1.f);
}

extern "C" __global__ void __launch_bounds__(256, 1) lstm_scan(
    const float* __restrict__ x, const float* __restrict__ W,
    const float* __restrict__ U, const float* __restrict__ bias,
    float* __restrict__ wsf)
{
    extern __shared__ float lds[];
    float* Ws   = lds + OFF_WS;
    float* z    = lds + OFF_Z;
    float* part = lds + OFF_PART;
    float* gb   = lds + OFF_GB;
    float* cst  = lds + OFF_CST;
    float* bia  = lds + OFF_BIA;
    int*   misc = (int*)(lds + OFF_MISC);

    int* abortp = (int*)wsf;
    u64* hbuf   = (u64*)((char*)wsf + WS_HBUF_B);   // [2][64][256] tagged

    const int tid = threadIdx.x;
    const int gid = blockIdx.x & 15;      // group
    const int p   = blockIdx.x >> 4;      // member: owns h-indices [16p,16p+16)
    const int cg  = tid & 15;             // column group (4 cols)
    const int rc  = tid >> 4;             // row group (rows 4rc + 64rr)

    // rc-dependent column rotation for the b128 weight reads (store+read consistent;
    // acc[bg][c] is logical column cg*4+c — partials stored at logical index)
    const int rotcol = ((cg * 4) + (rc & 3) * 8) & 63;

    // ---- stage weight slice: rows 0..127 = W, 128..383 = U; cols = gate*256+16p+j
    for (int idx = tid; idx < KR * NCOL; idx += 256) {
        int r = idx >> 6, c = idx & 63;
        int gate = c >> 4, j = c & 15;
        int gcol = gate * HH + p * 16 + j;
        float v = (r < II) ? W[r * 1024 + gcol] : U[(r - II) * 1024 + gcol];
        Ws[r * WS_STRIDE + ((c + ((r >> 2) & 3) * 8) & 63)] = v;
    }
    if (tid < NCOL) {
        int gate = tid >> 4, j = tid & 15;
        bia[tid] = bias[gate * HH + p * 16 + j];
    }
    if (tid < 64) cst[tid] = 0.f;
    for (int idx = tid; idx < 4 * Z_STRIDE; idx += 256) z[idx] = 0.f;
    if (tid < 8) misc[tid] = 0;

    const int lane = tid & 63;
    const int bgw  = tid >> 6;            // wave index == batch-in-group

    // ---- prologue: x_1 into z
    if (tid < 128) {
        const int b2 = tid >> 5, l2 = tid & 31;
        const float4 xv = *(const float4*)(
            x + ((size_t)(4 * gid + b2) * TT + 0) * II + 4 * l2);
        *(float4*)(z + b2 * Z_STRIDE + 4 * l2) = xv;
    }
    __syncthreads();

    for (int t = 1; t <= TT; ++t) {
        float acc[4][4];
#pragma unroll
        for (int a = 0; a < 4; ++a)
#pragma unroll
            for (int b = 0; b < 4; ++b) acc[a][b] = 0.f;

        // ---- matvec over x rows (0..127): h-independent
#pragma unroll
        for (int rr = 0; rr < 2; ++rr) {
            const int rowb = rr * 64 + rc * 4;
            const float* wbase = Ws + rowb * WS_STRIDE + rotcol;
            const float4 w0 = *(const float4*)(wbase);
            const float4 w1 = *(const float4*)(wbase + WS_STRIDE);
            const float4 w2 = *(const float4*)(wbase + 2 * WS_STRIDE);
            const float4 w3 = *(const float4*)(wbase + 3 * WS_STRIDE);
            const float* zrow = z + rowb;
#pragma unroll
            for (int bg = 0; bg < 4; ++bg) {
                const float4 zv = *(const float4*)(zrow + bg * Z_STRIDE);
                acc[bg][0] += zv.x * w0.x; acc[bg][1] += zv.x * w0.y;
                acc[bg][2] += zv.x * w0.z; acc[bg][3] += zv.x * w0.w;
                acc[bg][0] += zv.y * w1.x; acc[bg][1] += zv.y * w1.y;
                acc[bg][2] += zv.y * w1.z; acc[bg][3] += zv.y * w1.w;
                acc[bg][0] += zv.z * w2.x; acc[bg][1] += zv.z * w2.y;
                acc[bg][2] += zv.z * w2.z; acc[bg][3] += zv.z * w2.w;
                acc[bg][0] += zv.w * w3.x; acc[bg][1] += zv.w * w3.y;
                acc[bg][2] += zv.w * w3.z; acc[bg][3] += zv.w * w3.w;
            }
        }

        // ---- tagged poll: each wave pulls its OWN batch's h_{t-1} (detect==data)
        if (t > 1) {
            const unsigned want = (unsigned)(t - 1);
            const u64* hsrc = hbuf + ((size_t)((t - 1) & 1) * BB + 4 * gid + bgw) * HH;
            u64 v0 = 0, v1 = 0, v2 = 0, v3 = 0;
            bool k0 = false, k1 = false, k2 = false, k3 = false;
            int it = 0, ab = 0;
            for (;;) {
                if (!k0) { v0 = __hip_atomic_load(hsrc + lane,       __ATOMIC_RELAXED, __HIP_MEMORY_SCOPE_AGENT); k0 = ((unsigned)(v0 >> 32) == want); }
                if (!k1) { v1 = __hip_atomic_load(hsrc + lane + 64,  __ATOMIC_RELAXED, __HIP_MEMORY_SCOPE_AGENT); k1 = ((unsigned)(v1 >> 32) == want); }
                if (!k2) { v2 = __hip_atomic_load(hsrc + lane + 128, __ATOMIC_RELAXED, __HIP_MEMORY_SCOPE_AGENT); k2 = ((unsigned)(v2 >> 32) == want); }
                if (!k3) { v3 = __hip_atomic_load(hsrc + lane + 192, __ATOMIC_RELAXED, __HIP_MEMORY_SCOPE_AGENT); k3 = ((unsigned)(v3 >> 32) == want); }
                if (__ballot(k0 && k1 && k2 && k3) == ~0ULL) break;
                if ((++it & 63) == 0) {
                    int abv = __hip_atomic_load(abortp, __ATOMIC_RELAXED,
                                                __HIP_MEMORY_SCOPE_AGENT);
                    if (abv) { ab = 1; break; }
                    if (it > (1 << 18)) {
                        if (lane == 0)
                            __hip_atomic_store(abortp, 1, __ATOMIC_RELAXED,
                                               __HIP_MEMORY_SCOPE_AGENT);
                        ab = 1; break;
                    }
                }
            }
            if (lane == 0) misc[bgw] = ab;
            float* zdst = z + bgw * Z_STRIDE + II + lane;
            zdst[0]   = __uint_as_float((unsigned)v0);
            zdst[64]  = __uint_as_float((unsigned)v1);
            zdst[128] = __uint_as_float((unsigned)v2);
            zdst[192] = __uint_as_float((unsigned)v3);
        }
        __syncthreads();
        if (misc[0] | misc[1] | misc[2] | misc[3]) break;

        // ---- matvec over h rows (128..383)
#pragma unroll
        for (int rr = 2; rr < 6; ++rr) {
            const int rowb = rr * 64 + rc * 4;
            const float* wbase = Ws + rowb * WS_STRIDE + rotcol;
            const float4 w0 = *(const float4*)(wbase);
            const float4 w1 = *(const float4*)(wbase + WS_STRIDE);
            const float4 w2 = *(const float4*)(wbase + 2 * WS_STRIDE);
            const float4 w3 = *(const float4*)(wbase + 3 * WS_STRIDE);
            const float* zrow = z + rowb;
#pragma unroll
            for (int bg = 0; bg < 4; ++bg) {
                const float4 zv = *(const float4*)(zrow + bg * Z_STRIDE);
                acc[bg][0] += zv.x * w0.x; acc[bg][1] += zv.x * w0.y;
                acc[bg][2] += zv.x * w0.z; acc[bg][3] += zv.x * w0.w;
                acc[bg][0] += zv.y * w1.x; acc[bg][1] += zv.y * w1.y;
                acc[bg][2] += zv.y * w1.z; acc[bg][3] += zv.y * w1.w;
                acc[bg][0] += zv.z * w2.x; acc[bg][1] += zv.z * w2.y;
                acc[bg][2] += zv.z * w2.z; acc[bg][3] += zv.z * w2.w;
                acc[bg][0] += zv.w * w3.x; acc[bg][1] += zv.w * w3.y;
                acc[bg][2] += zv.w * w3.z; acc[bg][3] += zv.w * w3.w;
            }
        }

        // ---- partials to LDS at LOGICAL column index
#pragma unroll
        for (int bg = 0; bg < 4; ++bg)
#pragma unroll
            for (int c = 0; c < 4; ++c)
                part[rc * PART_RC_STRIDE + bg * PART_BG_STRIDE + cg * 4 + c] = acc[bg][c];
        __syncthreads();

        // ---- reduce over 16 row-groups + bias
        {
            const int bg = tid >> 6, col = tid & 63;
            float s = 0.f;
#pragma unroll
            for (int r2 = 0; r2 < 16; ++r2)
                s += part[r2 * PART_RC_STRIDE + bg * PART_BG_STRIDE + col];
            gb[bg * 64 + col] = s + bia[col];
        }
        __syncthreads();

        // ---- gates (wave 0, fast-math) + tagged publish || x_{t+1} prefetch
        if (tid < 64) {
            const int bg = tid >> 4, j = tid & 15;
            const float gi = gb[bg * 64 + j];
            const float gf = gb[bg * 64 + 16 + j];
            const float gg = gb[bg * 64 + 32 + j];
            const float go = gb[bg * 64 + 48 + j];
            const float iv = sigm(gi);
            const float fv = sigm(gf);
            const float gv = ftanh(gg);
            const float ov = sigm(go);
            const float cv = fv * cst[tid] + iv * gv;
            cst[tid] = cv;
            const float hv = ov * ftanh(cv);
            const u64 pk = ((u64)(unsigned)t << 32) | (u64)__float_as_uint(hv);
            __hip_atomic_store(
                hbuf + ((size_t)(t & 1) * BB + 4 * gid + bg) * HH + p * 16 + j,
                pk, __ATOMIC_RELAXED, __HIP_MEMORY_SCOPE_AGENT);
        } else if (tid >= 128 && t < TT) {
            const int i2 = tid - 128;
            const int b2 = i2 >> 5, l2 = i2 & 31;
            const float4 xv = *(const float4*)(
                x + ((size_t)(4 * gid + b2) * TT + t) * II + 4 * l2);
            *(float4*)(z + b2 * Z_STRIDE + 4 * l2) = xv;
        }
        asm volatile("" ::: "memory");
        __syncthreads();
    }
}

extern "C" __global__ void __launch_bounds__(256) lstm_out(
    const float* __restrict__ wsf, const float* __restrict__ dw,
    const float* __restrict__ db, float* __restrict__ out)
{
    __shared__ float hs[256];
    __shared__ float red[256];
    const int b = blockIdx.x;
    const int tid = threadIdx.x;
    const u64* h0 = (const u64*)((const char*)wsf + WS_HBUF_B);  // parity 0 = h_1024
    hs[tid] = __uint_as_float((unsigned)h0[(size_t)b * HH + tid]);
    __syncthreads();
    const int o = tid & 127, half = tid >> 7;
    const float* wrow = dw + o * HH + half * 128;
    const float* hrow = hs + half * 128;
    float s = 0.f;
#pragma unroll
    for (int k = 0; k < 128; k += 4) {
        const float4 wv = *(const float4*)(wrow + k);
        s += hrow[k] * wv.x + hrow[k + 1] * wv.y + hrow[k + 2] * wv.z + hrow[k + 3] * wv.w;
    }
    red[tid] = s;
    __syncthreads();
    if (tid < 128)
        out[(size_t)b * OO + tid] = red[tid] + red[128 + tid] + db[tid];
}

extern "C" void kernel_launch(void* const* d_in, const int* in_sizes, int n_in,
                              void* d_out, int out_size, void* d_ws, size_t ws_size,
                              hipStream_t stream)
{
    const float* x    = (const float*)d_in[0];
    const float* W    = (const float*)d_in[1];
    const float* U    = (const float*)d_in[2];
    const float* bias = (const float*)d_in[3];
    const float* dw   = (const float*)d_in[4];
    const float* db   = (const float*)d_in[5];
    float* out = (float*)d_out;
    float* ws  = (float*)d_ws;

    hipFuncSetAttribute((const void*)lstm_scan,
                        hipFuncAttributeMaxDynamicSharedMemorySize, LDS_BYTES);
    // zero abort + tagged hbuf each call (tag=0 never matches t>=1 -> no
    // cross-replay staleness)
    hipMemsetAsync(d_ws, 0, WS_CLEAR_B, stream);
    hipLaunchKernelGGL(lstm_scan, dim3(256), dim3(256), LDS_BYTES, stream,
                       x, W, U, bias, ws);
    hipLaunchKernelGGL(lstm_out, dim3(64), dim3(256), 0, stream, ws, dw, db, out);
}

// Round 7
// 2418.825 us; speedup vs baseline: 1.4323x; 1.4323x over previous
//
#include <hip/hip_runtime.h>
#include <math.h>

#define TT 1024
#define BB 64
#define II 128
#define HH 256
#define OO 128
#define KR 384           // II + HH rows of [W;U]
#define GPB 16           // blocks per group
#define NCOL 64          // gate-columns per block
#define Z_STRIDE 392     // padded z row stride per batch (floats)
#define PART_BG_STRIDE 68
#define PART_RC_STRIDE 273

// ws layout: per-block flags (256 x 8-int stride = 8KB), abort @int 2048,
// hbuf (2*64*256 floats) @byte 16384
#define WS_HBUF_F 4096

__device__ __forceinline__ float rcp(float v) { return __builtin_amdgcn_rcpf(v); }
__device__ __forceinline__ float sigm(float v) { return rcp(1.f + __expf(-v)); }
__device__ __forceinline__ float ftanh(float v) {
    return __builtin_fmaf(-2.f, rcp(__expf(2.f * v) + 1.f), 1.f);
}

extern "C" __global__ void __launch_bounds__(256, 1) lstm_scan(
    const float* __restrict__ x, const float* __restrict__ W,
    const float* __restrict__ U, const float* __restrict__ bias,
    float* __restrict__ wsf)
{
    __shared__ float z[4 * Z_STRIDE];
    __shared__ float part[16 * PART_RC_STRIDE];
    __shared__ float gb[256];
    __shared__ float cst[64];
    __shared__ float bia[64];
    __shared__ int   misc[8];

    int*   flags  = (int*)wsf;            // per-block flag, stride 8 ints (32B)
    int*   abortp = ((int*)wsf) + 2048;
    float* hbuf   = wsf + WS_HBUF_F;      // [2][64][256]

    const int tid = threadIdx.x;
    const int gid = blockIdx.x & 15;      // group
    const int p   = blockIdx.x >> 4;      // member: owns h-indices [16p,16p+16)
    const int cg  = tid & 15;             // column group (4 logical cols cg*4..+3)
    const int rc  = tid >> 4;             // row group (rows rr*64 + rc*4 .. +3)

    // ---- weights in VGPRs: wr[rr][i][c] = [W;U][rr*64+rc*4+i][logical col cg*4+c]
    // rr<2 -> W rows (0..127), rr>=2 -> U rows (128..383). 96 VGPRs/thread.
    float wr[6][4][4];
    {
        const int c0 = cg * 4;
        const int gate = c0 >> 4, j = c0 & 15;
        const int gcol = gate * HH + p * 16 + j;   // 4 consecutive cols from here
#pragma unroll
        for (int rr = 0; rr < 6; ++rr) {
#pragma unroll
            for (int i = 0; i < 4; ++i) {
                const int r = rr * 64 + rc * 4 + i;
                const float4 wv = (rr < 2)
                    ? *(const float4*)(W + (size_t)r * 1024 + gcol)
                    : *(const float4*)(U + (size_t)(r - II) * 1024 + gcol);
                wr[rr][i][0] = wv.x; wr[rr][i][1] = wv.y;
                wr[rr][i][2] = wv.z; wr[rr][i][3] = wv.w;
            }
        }
    }

    if (tid < NCOL) {
        int gate = tid >> 4, j = tid & 15;
        bia[tid] = bias[gate * HH + p * 16 + j];
    }
    if (tid < 64) cst[tid] = 0.f;
    for (int idx = tid; idx < 4 * Z_STRIDE; idx += 256) z[idx] = 0.f;
    if (tid < 8) misc[tid] = 0;

    const int lane = tid & 63;
    const int bgw  = tid >> 6;            // wave index == batch-in-group

    // ---- prologue: x_1 into z
    if (tid < 128) {
        const int b2 = tid >> 5, l2 = tid & 31;
        const float4 xv = *(const float4*)(
            x + ((size_t)(4 * gid + b2) * TT + 0) * II + 4 * l2);
        *(float4*)(z + b2 * Z_STRIDE + 4 * l2) = xv;
    }
    __syncthreads();

    for (int t = 1; t <= TT; ++t) {
        float acc[4][4];
#pragma unroll
        for (int a = 0; a < 4; ++a)
#pragma unroll
            for (int b = 0; b < 4; ++b) acc[a][b] = 0.f;

        // ---- matvec over x rows (rr 0..1): h-independent, before the wait
#pragma unroll
        for (int rr = 0; rr < 2; ++rr) {
#pragma unroll
            for (int bg = 0; bg < 4; ++bg) {
                const float4 zv = *(const float4*)(z + bg * Z_STRIDE + rr * 64 + rc * 4);
#pragma unroll
                for (int c = 0; c < 4; ++c)
                    acc[bg][c] += zv.x * wr[rr][0][c] + zv.y * wr[rr][1][c]
                                + zv.z * wr[rr][2][c] + zv.w * wr[rr][3][c];
            }
        }

        // ---- wait: wave 0 polls all 16 member flags; 2 outstanding loads
        if (t > 1) {
            if (tid < 64) {
                const int need = t - 1;
                const int* fp = &flags[((lane & 15) * 16 + gid) * 8];
                int it = 0, ab = 0;
                for (;;) {
                    int f1 = need, f2 = need;
                    if (lane < GPB) {
                        f1 = __hip_atomic_load(fp, __ATOMIC_RELAXED,
                                               __HIP_MEMORY_SCOPE_AGENT);
                        f2 = __hip_atomic_load(fp, __ATOMIC_RELAXED,
                                               __HIP_MEMORY_SCOPE_AGENT);
                    }
                    if (__ballot(f1 >= need) == ~0ULL) break;
                    if (__ballot(f2 >= need) == ~0ULL) break;
                    if ((++it & 63) == 0) {
                        int abv = __hip_atomic_load(abortp, __ATOMIC_RELAXED,
                                                    __HIP_MEMORY_SCOPE_AGENT);
                        if (abv) { ab = 1; break; }
                        if (it > (1 << 19)) {
                            if (lane == 0)
                                __hip_atomic_store(abortp, 1, __ATOMIC_RELAXED,
                                                   __HIP_MEMORY_SCOPE_AGENT);
                            ab = 1; break;
                        }
                    }
                }
                if (lane == 0) misc[1] = ab;
            }
            __syncthreads();
            asm volatile("" ::: "memory");
            if (misc[1]) break;

            // load h_{t-1}: 4 independent atomic loads issued back-to-back
            // (registers first, LDS writes after -> ONE round-trip latency)
            const float* hsrc = hbuf + ((size_t)((t - 1) & 1) * BB + 4 * gid + bgw) * HH;
            const float v0 = __hip_atomic_load(hsrc + lane,       __ATOMIC_RELAXED, __HIP_MEMORY_SCOPE_AGENT);
            const float v1 = __hip_atomic_load(hsrc + lane + 64,  __ATOMIC_RELAXED, __HIP_MEMORY_SCOPE_AGENT);
            const float v2 = __hip_atomic_load(hsrc + lane + 128, __ATOMIC_RELAXED, __HIP_MEMORY_SCOPE_AGENT);
            const float v3 = __hip_atomic_load(hsrc + lane + 192, __ATOMIC_RELAXED, __HIP_MEMORY_SCOPE_AGENT);
            float* zdst = z + bgw * Z_STRIDE + II + lane;
            zdst[0]   = v0;
            zdst[64]  = v1;
            zdst[128] = v2;
            zdst[192] = v3;
        }
        __syncthreads();

        // ---- matvec over h rows (rr 2..5)
#pragma unroll
        for (int rr = 2; rr < 6; ++rr) {
#pragma unroll
            for (int bg = 0; bg < 4; ++bg) {
                const float4 zv = *(const float4*)(z + bg * Z_STRIDE + rr * 64 + rc * 4);
#pragma unroll
                for (int c = 0; c < 4; ++c)
                    acc[bg][c] += zv.x * wr[rr][0][c] + zv.y * wr[rr][1][c]
                                + zv.z * wr[rr][2][c] + zv.w * wr[rr][3][c];
            }
        }

        // ---- partials to LDS at logical column index
#pragma unroll
        for (int bg = 0; bg < 4; ++bg)
#pragma unroll
            for (int c = 0; c < 4; ++c)
                part[rc * PART_RC_STRIDE + bg * PART_BG_STRIDE + cg * 4 + c] = acc[bg][c];
        __syncthreads();

        // ---- reduce over 16 row-groups + bias
        {
            const int bg = tid >> 6, col = tid & 63;
            float s = 0.f;
#pragma unroll
            for (int r2 = 0; r2 < 16; ++r2)
                s += part[r2 * PART_RC_STRIDE + bg * PART_BG_STRIDE + col];
            gb[bg * 64 + col] = s + bia[col];
        }
        __syncthreads();

        // ---- gates (wave 0, fast-math) || x_{t+1} prefetch (waves 2,3)
        if (tid < 64) {
            const int bg = tid >> 4, j = tid & 15;
            const float gi = gb[bg * 64 + j];
            const float gf = gb[bg * 64 + 16 + j];
            const float gg = gb[bg * 64 + 32 + j];
            const float go = gb[bg * 64 + 48 + j];
            const float iv = sigm(gi);
            const float fv = sigm(gf);
            const float gv = ftanh(gg);
            const float ov = sigm(go);
            const float cv = fv * cst[tid] + iv * gv;
            cst[tid] = cv;
            const float hv = ov * ftanh(cv);
            __hip_atomic_store(
                hbuf + ((size_t)(t & 1) * BB + 4 * gid + bg) * HH + p * 16 + j,
                hv, __ATOMIC_RELAXED, __HIP_MEMORY_SCOPE_AGENT);
        } else if (tid >= 128 && t < TT) {
            const int i2 = tid - 128;
            const int b2 = i2 >> 5, l2 = i2 & 31;
            const float4 xv = *(const float4*)(
                x + ((size_t)(4 * gid + b2) * TT + t) * II + 4 * l2);
            *(float4*)(z + b2 * Z_STRIDE + 4 * l2) = xv;
        }
        asm volatile("" ::: "memory");
        __syncthreads();   // drains vmcnt(0): h stores ack'd before flag store
        if (tid == 0)
            __hip_atomic_store(&flags[blockIdx.x * 8], t,
                               __ATOMIC_RELAXED, __HIP_MEMORY_SCOPE_AGENT);
    }
}

extern "C" __global__ void __launch_bounds__(256) lstm_out(
    const float* __restrict__ wsf, const float* __restrict__ dw,
    const float* __restrict__ db, float* __restrict__ out)
{
    __shared__ float hs[256];
    __shared__ float red[256];
    const int b = blockIdx.x;
    const int tid = threadIdx.x;
    const float* h0 = wsf + WS_HBUF_F;   // parity 0 holds h_{1024}
    hs[tid] = h0[(size_t)b * HH + tid];
    __syncthreads();
    const int o = tid & 127, half = tid >> 7;
    const float* wrow = dw + o * HH + half * 128;
    const float* hrow = hs + half * 128;
    float s = 0.f;
#pragma unroll
    for (int k = 0; k < 128; k += 4) {
        const float4 wv = *(const float4*)(wrow + k);
        s += hrow[k] * wv.x + hrow[k + 1] * wv.y + hrow[k + 2] * wv.z + hrow[k + 3] * wv.w;
    }
    red[tid] = s;
    __syncthreads();
    if (tid < 128)
        out[(size_t)b * OO + tid] = red[tid] + red[128 + tid] + db[tid];
}

extern "C" void kernel_launch(void* const* d_in, const int* in_sizes, int n_in,
                              void* d_out, int out_size, void* d_ws, size_t ws_size,
                              hipStream_t stream)
{
    const float* x    = (const float*)d_in[0];
    const float* W    = (const float*)d_in[1];
    const float* U    = (const float*)d_in[2];
    const float* bias = (const float*)d_in[3];
    const float* dw   = (const float*)d_in[4];
    const float* db   = (const float*)d_in[5];
    float* out = (float*)d_out;
    float* ws  = (float*)d_ws;

    // zero flags + abort each call (monotone protocol restarts cleanly per replay)
    hipMemsetAsync(d_ws, 0, 16384, stream);
    hipLaunchKernelGGL(lstm_scan, dim3(256), dim3(256), 0, stream,
                       x, W, U, bias, ws);
    hipLaunchKernelGGL(lstm_out, dim3(64), dim3(256), 0, stream, ws, dw, db, out);
}